// Round 8
// baseline (284.927 us; speedup 1.0000x reference)
//
#include <hip/hip_runtime.h>

typedef unsigned short u16;
typedef unsigned int u32;

#define T_SEQ 2048
#define NHEAD 16
#define HDIM 64
#define CDIM 1024
#define W_HSTR (512*2048)
#define Z_HSTR (2048*512)
// P: per head 136 causal tiles of 128x128 fp16, row-major tiles
#define P_HSTR 2228224   // 136*16384 elems
#define P_TILE 16384

// Octonion sign table: SG[a][n] = sign of component (a^n) of e_a * e_n.
// Byte a holds row a; bit n set => negative. (Validated end-to-end rounds 3-8.)
#define SGBITS 0xB2D8741EACC66A00ULL

// exp(s*0.125) = exp2(s*0.125/ln2); extra 2^-12 scale keeps unnormalized Z in fp16 range.
#define EXP2C 0.18033688011112042f

// s_waitcnt imm: [3:0] vmcnt lo, [6:4] exp (7=nowait), [11:8] lgkm (F=nowait), [15:14] vmcnt hi
#define WAITCNT_VM0 0x0F70

typedef _Float16 f16x8 __attribute__((ext_vector_type(8)));
typedef float f32x4 __attribute__((ext_vector_type(4)));

__device__ __forceinline__ float h2f(u16 u) { _Float16 h; __builtin_memcpy(&h, &u, 2); return (float)h; }
__device__ __forceinline__ u16 f2h(float f) { _Float16 h = (_Float16)f; u16 u; __builtin_memcpy(&u, &h, 2); return u; }
__device__ __forceinline__ u32 pk(float a, float b) { return (u32)f2h(a) | ((u32)f2h(b) << 16); }

// async 16B/lane global->LDS DMA; lds dest wave-uniform (HW adds lane*16)
__device__ __forceinline__ void gload16(const u16* g, u16* l) {
    __builtin_amdgcn_global_load_lds((const __attribute__((address_space(1))) u32*)g,
                                     (__attribute__((address_space(3))) u32*)l, 16, 0, 0);
}

// ---- MFMA tile core (conflict-free fragment-major LDS; rounds 6-8) ----
template<bool F16OUT>
__device__ __forceinline__ void hgemm_tile(const u16* __restrict__ At, int lda,
                                           const u16* __restrict__ Bt, int ldb, int K,
                                           float* __restrict__ Cf, u16* __restrict__ Ch,
                                           int ldc, float scale, u16* As, u16* Bs) {
    int t = threadIdx.x;
    int wave = t >> 6, l = t & 63;
    int wm = wave & 1, wn = wave >> 1;
    int quad = l >> 4, lr = l & 15;
    f32x4 acc[4][4];
#pragma unroll
    for (int i = 0; i < 4; ++i)
#pragma unroll
        for (int j = 0; j < 4; ++j) acc[i][j] = (f32x4){0.f, 0.f, 0.f, 0.f};
    int acol = quad * 8;
    for (int k0 = 0; k0 < K; k0 += 64) {
#pragma unroll
        for (int j = 0; j < 4; ++j) {
            int d = wave * 4 + j;
            int kb = d >> 3, seg = d & 7;
            size_t roff = (size_t)(seg * 16 + lr);
            int coff = k0 + kb * 32 + acol;
            gload16(At + roff * lda + coff, As + d * 512);
            gload16(Bt + roff * ldb + coff, Bs + d * 512);
        }
        __syncthreads();
#pragma unroll
        for (int kb = 0; kb < 2; ++kb) {
            f16x8 af[4], bf[4];
#pragma unroll
            for (int mi = 0; mi < 4; ++mi) af[mi] = *(const f16x8*)&As[(kb * 8 + wm * 4 + mi) * 512 + l * 8];
#pragma unroll
            for (int ni = 0; ni < 4; ++ni) bf[ni] = *(const f16x8*)&Bs[(kb * 8 + wn * 4 + ni) * 512 + l * 8];
#pragma unroll
            for (int mi = 0; mi < 4; ++mi)
#pragma unroll
                for (int ni = 0; ni < 4; ++ni)
                    acc[mi][ni] = __builtin_amdgcn_mfma_f32_16x16x32_f16(af[mi], bf[ni], acc[mi][ni], 0, 0, 0);
        }
        __syncthreads();
    }
#pragma unroll
    for (int mi = 0; mi < 4; ++mi)
#pragma unroll
        for (int ni = 0; ni < 4; ++ni)
#pragma unroll
            for (int rr = 0; rr < 4; ++rr) {
                int gr = wm * 64 + mi * 16 + quad * 4 + rr;
                int gc = wn * 64 + ni * 16 + lr;
                float v = acc[mi][ni][rr] * scale;
                if (F16OUT) Ch[(size_t)gr * ldc + gc] = f2h(v);
                else Cf[(size_t)gr * ldc + gc] = v;
            }
}

__global__ __launch_bounds__(256) void hgemm_f32(const u16* __restrict__ A, int lda,
                                                 const u16* __restrict__ B, int ldb,
                                                 float* __restrict__ C, int ldc, int K) {
    __shared__ u16 As[8192], Bs[8192];
    int bm = blockIdx.y * 128, bn = blockIdx.x * 128;
    hgemm_tile<false>(A + (size_t)bm * lda, lda, B + (size_t)bn * ldb, ldb, K,
                      C + (size_t)bm * ldc + bn, nullptr, ldc, 1.f, As, Bs);
}

__global__ __launch_bounds__(256) void hgemm_f16(const u16* __restrict__ A, int lda,
                                                 const u16* __restrict__ B, int ldb,
                                                 u16* __restrict__ C, int ldc, int K) {
    __shared__ u16 As[8192], Bs[8192];
    int bm = blockIdx.y * 128, bn = blockIdx.x * 128;
    hgemm_tile<true>(A + (size_t)bm * lda, lda, B + (size_t)bn * ldb, ldb, K,
                     nullptr, C + (size_t)bm * ldc + bn, ldc, 1.f, As, Bs);
}

// ---- Kernel A: one-shot P = exp(QK^T) per 128x128 causal tile ----
// 2176 blocks = 16 heads x 136 tiles (rb>=cb). QK direct from global (L2-resident),
// exp -> LDS (round-0 expst pattern), then coalesced row-major uint4 tile store.
// LDS pad 144 keeps 16B alignment for the uint4 re-read (144*2 = 288 = 18*16).
__global__ __launch_bounds__(256) void qk_exp_p(const u16* __restrict__ q16,
                                                const u16* __restrict__ k16,
                                                u16* __restrict__ P) {
    __shared__ u16 Pt[128 * 144];
    int idx = blockIdx.x;
    int h = idx & 15;
    int tt = idx >> 4;                   // 0..135 triangular tile index
    int rb = 0;
    while ((rb + 1) * (rb + 2) / 2 <= tt) rb++;
    int cb = tt - rb * (rb + 1) / 2;     // 0..rb
    int t = threadIdx.x;
    int wave = t >> 6, l = t & 63;
    int wm = wave & 1, wn = wave >> 1;
    int quad = l >> 4, lr = l & 15;

    const u16* qbase = q16 + (size_t)(rb * 128 + wm * 64 + lr) * CDIM + h * HDIM + quad * 8;
    const u16* kbase = k16 + (size_t)(cb * 128 + wn * 64 + lr) * CDIM + h * HDIM + quad * 8;
    f16x8 qa[4][2], kf[4][2];
#pragma unroll
    for (int mi = 0; mi < 4; ++mi)
#pragma unroll
        for (int kb = 0; kb < 2; ++kb)
            qa[mi][kb] = *(const f16x8*)(qbase + (size_t)(mi * 16) * CDIM + kb * 32);
#pragma unroll
    for (int ni = 0; ni < 4; ++ni)
#pragma unroll
        for (int kb = 0; kb < 2; ++kb)
            kf[ni][kb] = *(const f16x8*)(kbase + (size_t)(ni * 16) * CDIM + kb * 32);

    f32x4 s[4][4];
#pragma unroll
    for (int mi = 0; mi < 4; ++mi)
#pragma unroll
        for (int ni = 0; ni < 4; ++ni) s[mi][ni] = (f32x4){0.f, 0.f, 0.f, 0.f};
#pragma unroll
    for (int kb = 0; kb < 2; ++kb)
#pragma unroll
        for (int mi = 0; mi < 4; ++mi)
#pragma unroll
            for (int ni = 0; ni < 4; ++ni)
                s[mi][ni] = __builtin_amdgcn_mfma_f32_16x16x32_f16(qa[mi][kb], kf[ni][kb], s[mi][ni], 0, 0, 0);

#pragma unroll
    for (int mi = 0; mi < 4; ++mi) {
        int row = wm * 64 + mi * 16 + quad * 4;
#pragma unroll
        for (int ni = 0; ni < 4; ++ni) {
            int col = wn * 64 + ni * 16 + lr;
#pragma unroll
            for (int rr = 0; rr < 4; ++rr) {
                bool valid = (cb < rb) | (col <= row + rr);   // same 128-block => local compare
                float p = valid ? __builtin_amdgcn_exp2f(s[mi][ni][rr] * EXP2C - 12.f) : 0.f;
                Pt[(row + rr) * 144 + col] = f2h(p);
            }
        }
    }
    __syncthreads();
    u16* Pg = P + (size_t)h * P_HSTR + (size_t)tt * P_TILE;
#pragma unroll
    for (int i = 0; i < 8; ++i) {
        int c = i * 256 + t;             // 2048 chunks of 8 elems
        int row = c >> 4, cw = c & 15;
        uint4 v = *(const uint4*)&Pt[row * 144 + cw * 8];
        *(uint4*)(Pg + row * 128 + cw * 8) = v;
    }
}

// ---- Kernel B: Z = P @ W, 8-wave paired-job blocks + STATIC double-buffer ----
// Round-7 dbuf was null: dynamic As[cur] indexing defeats LDS alias analysis, so the
// compiler inserted its own vmcnt(0) before the compute ds_reads (prefetch compiled
// away). Round-8 fix: four distinct __shared__ arrays + 2-step unrolled loop with
// STATIC buffer names -> compiler proves ds_read(A0s) disjoint from gload_lds->A1s
// and lets the prefetch ride over the MFMA phase. Explicit vmcnt(0)+s_barrier at each
// phase end keeps correctness (wait = this phase's prefetch; barrier = buffer handoff).
// Paired jobs kept (17 K-units/block, zero tail); 2 blocks/CU x 8 waves = 16 waves/CU.
// l = P.1 via ones-MFMA on nq==0, wc==0 waves; 1/l deferred to contract_y.
__global__ __launch_bounds__(512, 4) void pw_gemm(const u16* __restrict__ P,
                                                  const u16* __restrict__ W,
                                                  u16* __restrict__ Z,
                                                  float* __restrict__ lbuf) {
    __shared__ u16 A0s[8192], B0s[8192], A1s[8192], B1s[8192];
    int b = blockIdx.x;
    int jp = b >> 6;                     // 0..7 rb-pair index
    int i6 = b & 63;
    int h = ((i6 & 7) << 1) | ((i6 >> 3) & 1);
    int nq = i6 >> 4;
    const u16* Bt = W + (size_t)h * W_HSTR + (size_t)(nq * 128) * T_SEQ;
    u16* Zb = Z + (size_t)h * Z_HSTR;
    int t = threadIdx.x;
    int wave = t >> 6, l = t & 63;
    int wr = wave >> 1, wc = wave & 1;   // wave tile: rows wr*32, cols wc*64
    int quad = l >> 4, lr = l & 15;
    int acol = quad * 8;
    // per-wave staging slots d0,d1 (same fragment-major formulas as rounds 6-7)
    int d0 = wave * 2, d1 = wave * 2 + 1;
    int kq0 = d0 >> 3, sg0 = d0 & 7;
    int kq1 = d1 >> 3, sg1 = d1 & 7;
    size_t ro0 = (size_t)(sg0 * 16 + lr), ro1 = (size_t)(sg1 * 16 + lr);
    f16x8 ones;
#pragma unroll
    for (int j = 0; j < 8; ++j) ones[j] = (_Float16)1.0f;

    const u16* Ph;
    f32x4 acc[2][4];
    f32x4 accl[2];

    auto stage = [&](int k0, u16* Ad, u16* Bd) {
        const u16* At = Ph + (size_t)(k0 >> 7) * P_TILE + (k0 & 64);  // tile base + k-half
        gload16(At + ro0 * 128 + kq0 * 32 + acol, Ad + d0 * 512);
        gload16(Bt + ro0 * T_SEQ + k0 + kq0 * 32 + acol, Bd + d0 * 512);
        gload16(At + ro1 * 128 + kq1 * 32 + acol, Ad + d1 * 512);
        gload16(Bt + ro1 * T_SEQ + k0 + kq1 * 32 + acol, Bd + d1 * 512);
    };
    auto compute = [&](const u16* Asrc, const u16* Bsrc, bool dol) {
#pragma unroll
        for (int kb = 0; kb < 2; ++kb) {
            f16x8 af[2], bf[4];
#pragma unroll
            for (int mi = 0; mi < 2; ++mi) af[mi] = *(const f16x8*)&Asrc[(kb * 8 + wr * 2 + mi) * 512 + l * 8];
#pragma unroll
            for (int ni = 0; ni < 4; ++ni) bf[ni] = *(const f16x8*)&Bsrc[(kb * 8 + wc * 4 + ni) * 512 + l * 8];
#pragma unroll
            for (int mi = 0; mi < 2; ++mi) {
#pragma unroll
                for (int ni = 0; ni < 4; ++ni)
                    acc[mi][ni] = __builtin_amdgcn_mfma_f32_16x16x32_f16(af[mi], bf[ni], acc[mi][ni], 0, 0, 0);
                if (dol)
                    accl[mi] = __builtin_amdgcn_mfma_f32_16x16x32_f16(af[mi], ones, accl[mi], 0, 0, 0);
            }
        }
    };

#pragma unroll 1
    for (int jobi = 0; jobi < 2; ++jobi) {
        int rb = jobi ? jp : 15 - jp;    // heavy job first
        int nsteps = (rb + 1) * 2;       // K/64, always even
        Ph = P + (size_t)h * P_HSTR + (size_t)(rb * (rb + 1) / 2) * P_TILE;
        bool dol = (nq == 0) && (wc == 0);
#pragma unroll
        for (int mi = 0; mi < 2; ++mi) {
            accl[mi] = (f32x4){0.f, 0.f, 0.f, 0.f};
#pragma unroll
            for (int ni = 0; ni < 4; ++ni) acc[mi][ni] = (f32x4){0.f, 0.f, 0.f, 0.f};
        }
        // prologue: step 0 staged + drained
        stage(0, A0s, B0s);
        __builtin_amdgcn_s_waitcnt(WAITCNT_VM0);
        __builtin_amdgcn_s_barrier();
#pragma unroll 1
        for (int s = 0; s < nsteps; s += 2) {
            // even phase: prefetch s+1 -> buf1 (static names), compute buf0
            stage((s + 1) * 64, A1s, B1s);          // s+1 < nsteps always (nsteps even)
            compute(A0s, B0s, dol);
            __builtin_amdgcn_s_waitcnt(WAITCNT_VM0);
            __builtin_amdgcn_s_barrier();
            // odd phase: prefetch s+2 -> buf0, compute buf1
            if (s + 2 < nsteps) stage((s + 2) * 64, A0s, B0s);
            compute(A1s, B1s, dol);
            __builtin_amdgcn_s_waitcnt(WAITCNT_VM0);
            __builtin_amdgcn_s_barrier();
        }
#pragma unroll
        for (int mi = 0; mi < 2; ++mi)
#pragma unroll
            for (int rr = 0; rr < 4; ++rr) {
                int row = rb * 128 + wr * 32 + mi * 16 + quad * 4 + rr;
#pragma unroll
                for (int ni = 0; ni < 4; ++ni) {
                    int col = nq * 128 + wc * 64 + ni * 16 + lr;
                    Zb[(size_t)row * 512 + col] = f2h(acc[mi][ni][rr]);
                }
            }
        if (dol && lr == 0) {
#pragma unroll
            for (int mi = 0; mi < 2; ++mi) {
                int row = rb * 128 + wr * 32 + mi * 16 + quad * 4;
                *(f32x4*)(lbuf + h * T_SEQ + row) = accl[mi];
            }
        }
    }
}

// fp32 -> fp16 conversions: z=0 x(2M), z=1..4 Wq/Wk/Wv/Wo (1M each) into w16
__global__ __launch_bounds__(256) void cvt5(const float* __restrict__ x, const float* __restrict__ wq,
                                            const float* __restrict__ wk, const float* __restrict__ wv,
                                            const float* __restrict__ wo,
                                            u16* __restrict__ x16, u16* __restrict__ w16) {
    int z = blockIdx.y;
    size_t base = ((size_t)blockIdx.x * 256 + threadIdx.x) * 8;
    const float* src;
    u16* dst;
    size_t cnt;
    if (z == 0) { src = x; dst = x16; cnt = 2097152; }
    else if (z == 1) { src = wq; dst = w16; cnt = 1048576; }
    else if (z == 2) { src = wk; dst = w16 + 1048576; cnt = 1048576; }
    else if (z == 3) { src = wv; dst = w16 + 2097152; cnt = 1048576; }
    else { src = wo; dst = w16 + 3145728; cnt = 1048576; }
    if (base >= cnt) return;
    float4 f0 = *(const float4*)(src + base);
    float4 f1 = *(const float4*)(src + base + 4);
    uint4 o;
    o.x = pk(f0.x, f0.y); o.y = pk(f0.z, f0.w); o.z = pk(f1.x, f1.y); o.w = pk(f1.z, f1.w);
    *(uint4*)(dst + base) = o;
}

// One wave per (t,h): rotary+RMS from fp16 qkv (ld 3072); writes q16,k16 (fp16), kc (fp32).
__global__ __launch_bounds__(256) void prep_rope(const u16* __restrict__ qkv,
                                                 u16* __restrict__ q16, u16* __restrict__ k16,
                                                 float* __restrict__ kc,
                                                 const float* __restrict__ cosb, const float* __restrict__ sinb) {
    int wave = threadIdx.x >> 6, lane = threadIdx.x & 63;
    int idx = blockIdx.x * 4 + wave;
    int t = idx >> 4, h = idx & 15;
    int d = lane & 31;
    float cs = cosb[t * 32 + d];
    float sn = sinb[t * 32 + d];
    size_t b3 = (size_t)t * 3072 + h * HDIM;
    size_t b1 = (size_t)t * CDIM + h * HDIM;

    float xq = h2f(qkv[b3 + lane]);
    float oq = __shfl(xq, lane ^ 32);
    float rq = (lane < 32) ? fmaf(xq, cs, oq * sn) : fmaf(xq, cs, -oq * sn);
    float ssq = rq * rq;
#pragma unroll
    for (int m = 1; m < 64; m <<= 1) ssq += __shfl_xor(ssq, m);
    rq *= rsqrtf(ssq * (1.f / 64.f) + 1e-6f);
    q16[b1 + lane] = f2h(rq);

    float xk = h2f(qkv[b3 + 1024 + lane]);
    float ok = __shfl(xk, lane ^ 32);
    float rk = (lane < 32) ? fmaf(xk, cs, ok * sn) : fmaf(xk, cs, -ok * sn);
    float ssk = rk * rk;
#pragma unroll
    for (int m = 1; m < 64; m <<= 1) ssk += __shfl_xor(ssk, m);
    rk *= rsqrtf(ssk * (1.f / 64.f) + 1e-6f);
    k16[b1 + lane] = f2h(rk);

    float s8 = rk * rk;
    s8 += __shfl_xor(s8, 1); s8 += __shfl_xor(s8, 2); s8 += __shfl_xor(s8, 4);
    float sc2 = 1.f / fmaxf(sqrtf(s8), 1e-12f);
    float kcv = rk * sc2;
    if (lane & 7) kcv = -kcv;  // octonion conjugate
    kc[b1 + lane] = kcv;
}

// W[h][n=(m*64+a*8+e)][j] from kc (fp32, ld 1024) and v inside fp16 qkv (ld 3072, +2048)
__global__ __launch_bounds__(256) void w_pre(const float* __restrict__ kc, const u16* __restrict__ qkv,
                                             u16* __restrict__ W) {
    __shared__ float kcs[64][65];
    __shared__ float vs[64][65];
    int h = blockIdx.y;
    int j0 = blockIdx.x * 64;
    int t = threadIdx.x;
    int r = t >> 2, cq = (t & 3) * 16;
    const float* kp = kc + (size_t)(j0 + r) * CDIM + h * HDIM + cq;
    const u16* vp = qkv + (size_t)(j0 + r) * 3072 + 2048 + h * HDIM + cq;
#pragma unroll
    for (int u4 = 0; u4 < 4; ++u4) {
        float4 a = *(const float4*)(kp + u4 * 4);
        ushort4 b = *(const ushort4*)(vp + u4 * 4);
        kcs[r][cq + u4 * 4 + 0] = a.x; kcs[r][cq + u4 * 4 + 1] = a.y;
        kcs[r][cq + u4 * 4 + 2] = a.z; kcs[r][cq + u4 * 4 + 3] = a.w;
        vs[r][cq + u4 * 4 + 0] = h2f(b.x); vs[r][cq + u4 * 4 + 1] = h2f(b.y);
        vs[r][cq + u4 * 4 + 2] = h2f(b.z); vs[r][cq + u4 * 4 + 3] = h2f(b.w);
    }
    __syncthreads();
    int j = t & 63, g = t >> 6;
    u16* Wp = W + (size_t)h * W_HSTR + j0 + j;
    for (int ae = g * 16; ae < g * 16 + 16; ++ae) {
        int a = ae >> 3, e = ae & 7;
        u32 mask = 0;
#pragma unroll
        for (int qq = 0; qq < 8; ++qq) {
            int p = a ^ e ^ qq;
            u32 bit = (u32)(((SGBITS >> (a * 8 + p)) ^ (SGBITS >> ((e ^ qq) * 8 + qq))) & 1ULL);
            mask |= bit << qq;
        }
#pragma unroll
        for (int m = 0; m < 8; ++m) {
            float w = 0.f;
#pragma unroll
            for (int qq = 0; qq < 8; ++qq) {
                float t1 = kcs[j][m * 8 + (a ^ e ^ qq)] * vs[j][m * 8 + qq];
                w = ((mask >> qq) & 1) ? (w - t1) : (w + t1);
            }
            Wp[(size_t)(m * 64 + ae) * T_SEQ] = f2h(w);
        }
    }
}

// y16[i, h*64+m*8+e] = (sum_a q16[..m*8+a] * Z'[h][i][m*64+a*8+e]) / l[h][i]
__global__ __launch_bounds__(256) void contract_y(const u16* __restrict__ q16, const u16* __restrict__ Z,
                                                  const float* __restrict__ lbuf, u16* __restrict__ y16) {
    __shared__ u16 zb[4][512];
    int wave = threadIdx.x >> 6, lane = threadIdx.x & 63;
    int idx = blockIdx.x * 4 + wave;
    int i = idx >> 4, h = idx & 15;
    uint4 zv = *(const uint4*)(Z + (size_t)h * Z_HSTR + (size_t)i * 512 + lane * 8);
    *(uint4*)&zb[wave][lane * 8] = zv;
    int m = lane >> 3, e = lane & 7;
    const u16* qp = q16 + (size_t)i * CDIM + h * HDIM + m * 8;
    uint4 qb = *(const uint4*)qp;
    float qv[8];
    qv[0] = h2f(qb.x & 0xffff); qv[1] = h2f(qb.x >> 16);
    qv[2] = h2f(qb.y & 0xffff); qv[3] = h2f(qb.y >> 16);
    qv[4] = h2f(qb.z & 0xffff); qv[5] = h2f(qb.z >> 16);
    qv[6] = h2f(qb.w & 0xffff); qv[7] = h2f(qb.w >> 16);
    float linv = 1.f / lbuf[h * T_SEQ + i];
    __syncthreads();
    float acc = 0.f;
#pragma unroll
    for (int a = 0; a < 8; ++a) acc = fmaf(qv[a], h2f(zb[wave][m * 64 + a * 8 + e]), acc);
    y16[(size_t)i * CDIM + h * HDIM + lane] = f2h(acc * linv);
}

extern "C" void kernel_launch(void* const* d_in, const int* in_sizes, int n_in,
                              void* d_out, int out_size, void* d_ws, size_t ws_size,
                              hipStream_t stream) {
    const float* x = (const float*)d_in[0];
    const float* cosb = (const float*)d_in[1];
    const float* sinb = (const float*)d_in[2];
    const float* Wq = (const float*)d_in[3];
    const float* Wk = (const float*)d_in[4];
    const float* Wv = (const float*)d_in[5];
    const float* Wo = (const float*)d_in[6];
    float* out = (float*)d_out;
    char* base = (char*)d_ws;
    // workspace layout (~185 MB total; ws >= 243 MB proven)
    u16* qkv16 = (u16*)base;                      // 2048x3072 fp16   12,582,912 B
    float* kc = (float*)(base + 12582912);        // 2048x1024 fp32    8,388,608
    u16* x16 = (u16*)(base + 20971520);           //                   4,194,304
    u16* w16 = (u16*)(base + 25165824);           // 4x 1024x1024 fp16 8,388,608
    u16* q16 = (u16*)(base + 33554432);           //                   4,194,304
    u16* k16 = (u16*)(base + 37748736);           //                   4,194,304
    u16* y16 = (u16*)(base + 41943040);           //                   4,194,304
    u16* W = (u16*)(base + 46137344);             //                  33,554,432
    u16* Z = (u16*)(base + 79691776);             //                  33,554,432
    float* lbuf = (float*)(base + 113246208);     // 16x2048 fp32        131,072
    u16* Pbuf = (u16*)(base + 113377280);         // 16x136 tiles fp16 71,303,168 -> end 184,680,448

    cvt5<<<dim3(1024, 5), 256, 0, stream>>>(x, Wq, Wk, Wv, Wo, x16, w16);
    hgemm_f16<<<dim3(24, 16), 256, 0, stream>>>(x16, CDIM, w16, CDIM, qkv16, 3072, CDIM);
    prep_rope<<<T_SEQ * NHEAD / 4, 256, 0, stream>>>(qkv16, q16, k16, kc, cosb, sinb);
    qk_exp_p<<<16 * 136, 256, 0, stream>>>(q16, k16, Pbuf);
    w_pre<<<dim3(32, 16), 256, 0, stream>>>(kc, qkv16, W);
    pw_gemm<<<512, 512, 0, stream>>>(Pbuf, W, Z, lbuf);
    contract_y<<<NHEAD * T_SEQ / 4, 256, 0, stream>>>(q16, Z, lbuf, y16);
    hgemm_f32<<<dim3(8, 16), 256, 0, stream>>>(y16, CDIM, w16 + 3145728, CDIM, out, CDIM, CDIM);
}

// Round 9
// 284.079 us; speedup vs baseline: 1.0030x; 1.0030x over previous
//
#include <hip/hip_runtime.h>

typedef unsigned short u16;
typedef unsigned int u32;

#define T_SEQ 2048
#define NHEAD 16
#define HDIM 64
#define CDIM 1024
#define W_HSTR (512*2048)
#define Z_HSTR (2048*512)
// P: per head 136 causal tiles of 128x128 fp16, row-major tiles
#define P_HSTR 2228224   // 136*16384 elems
#define P_TILE 16384

// Octonion sign table: SG[a][n] = sign of component (a^n) of e_a * e_n.
// Byte a holds row a; bit n set => negative. (Validated end-to-end rounds 3-8.)
#define SGBITS 0xB2D8741EACC66A00ULL

// exp(s*0.125) = exp2(s*0.125/ln2); extra 2^-12 scale keeps unnormalized Z in fp16 range.
#define EXP2C 0.18033688011112042f

typedef _Float16 f16x8 __attribute__((ext_vector_type(8)));
typedef float f32x4 __attribute__((ext_vector_type(4)));

__device__ __forceinline__ float h2f(u16 u) { _Float16 h; __builtin_memcpy(&h, &u, 2); return (float)h; }
__device__ __forceinline__ u16 f2h(float f) { _Float16 h = (_Float16)f; u16 u; __builtin_memcpy(&u, &h, 2); return u; }
__device__ __forceinline__ u32 pk(float a, float b) { return (u32)f2h(a) | ((u32)f2h(b) << 16); }

// async 16B/lane global->LDS DMA; lds dest wave-uniform (HW adds lane*16)
__device__ __forceinline__ void gload16(const u16* g, u16* l) {
    __builtin_amdgcn_global_load_lds((const __attribute__((address_space(1))) u32*)g,
                                     (__attribute__((address_space(3))) u32*)l, 16, 0, 0);
}

// ---- MFMA tile core (conflict-free fragment-major LDS; rounds 6-8) ----
template<bool F16OUT>
__device__ __forceinline__ void hgemm_tile(const u16* __restrict__ At, int lda,
                                           const u16* __restrict__ Bt, int ldb, int K,
                                           float* __restrict__ Cf, u16* __restrict__ Ch,
                                           int ldc, float scale, u16* As, u16* Bs) {
    int t = threadIdx.x;
    int wave = t >> 6, l = t & 63;
    int wm = wave & 1, wn = wave >> 1;
    int quad = l >> 4, lr = l & 15;
    f32x4 acc[4][4];
#pragma unroll
    for (int i = 0; i < 4; ++i)
#pragma unroll
        for (int j = 0; j < 4; ++j) acc[i][j] = (f32x4){0.f, 0.f, 0.f, 0.f};
    int acol = quad * 8;
    for (int k0 = 0; k0 < K; k0 += 64) {
#pragma unroll
        for (int j = 0; j < 4; ++j) {
            int d = wave * 4 + j;
            int kb = d >> 3, seg = d & 7;
            size_t roff = (size_t)(seg * 16 + lr);
            int coff = k0 + kb * 32 + acol;
            gload16(At + roff * lda + coff, As + d * 512);
            gload16(Bt + roff * ldb + coff, Bs + d * 512);
        }
        __syncthreads();
#pragma unroll
        for (int kb = 0; kb < 2; ++kb) {
            f16x8 af[4], bf[4];
#pragma unroll
            for (int mi = 0; mi < 4; ++mi) af[mi] = *(const f16x8*)&As[(kb * 8 + wm * 4 + mi) * 512 + l * 8];
#pragma unroll
            for (int ni = 0; ni < 4; ++ni) bf[ni] = *(const f16x8*)&Bs[(kb * 8 + wn * 4 + ni) * 512 + l * 8];
#pragma unroll
            for (int mi = 0; mi < 4; ++mi)
#pragma unroll
                for (int ni = 0; ni < 4; ++ni)
                    acc[mi][ni] = __builtin_amdgcn_mfma_f32_16x16x32_f16(af[mi], bf[ni], acc[mi][ni], 0, 0, 0);
        }
        __syncthreads();
    }
#pragma unroll
    for (int mi = 0; mi < 4; ++mi)
#pragma unroll
        for (int ni = 0; ni < 4; ++ni)
#pragma unroll
            for (int rr = 0; rr < 4; ++rr) {
                int gr = wm * 64 + mi * 16 + quad * 4 + rr;
                int gc = wn * 64 + ni * 16 + lr;
                float v = acc[mi][ni][rr] * scale;
                if (F16OUT) Ch[(size_t)gr * ldc + gc] = f2h(v);
                else Cf[(size_t)gr * ldc + gc] = v;
            }
}

__global__ __launch_bounds__(256) void hgemm_f32(const u16* __restrict__ A, int lda,
                                                 const u16* __restrict__ B, int ldb,
                                                 float* __restrict__ C, int ldc, int K) {
    __shared__ u16 As[8192], Bs[8192];
    int bm = blockIdx.y * 128, bn = blockIdx.x * 128;
    hgemm_tile<false>(A + (size_t)bm * lda, lda, B + (size_t)bn * ldb, ldb, K,
                      C + (size_t)bm * ldc + bn, nullptr, ldc, 1.f, As, Bs);
}

__global__ __launch_bounds__(256) void hgemm_f16(const u16* __restrict__ A, int lda,
                                                 const u16* __restrict__ B, int ldb,
                                                 u16* __restrict__ C, int ldc, int K) {
    __shared__ u16 As[8192], Bs[8192];
    int bm = blockIdx.y * 128, bn = blockIdx.x * 128;
    hgemm_tile<true>(A + (size_t)bm * lda, lda, B + (size_t)bn * ldb, ldb, K,
                     nullptr, C + (size_t)bm * ldc + bn, ldc, 1.f, As, Bs);
}

// ---- Kernel A: one-shot P = exp(QK^T) per 128x128 causal tile ----
// 2176 blocks = 16 heads x 136 tiles (rb>=cb). QK direct from global (L2-resident),
// exp -> LDS (round-0 expst pattern), then coalesced row-major uint4 tile store.
// LDS pad 144 keeps 16B alignment for the uint4 re-read (144*2 = 288 = 18*16).
__global__ __launch_bounds__(256) void qk_exp_p(const u16* __restrict__ q16,
                                                const u16* __restrict__ k16,
                                                u16* __restrict__ P) {
    __shared__ u16 Pt[128 * 144];
    int idx = blockIdx.x;
    int h = idx & 15;
    int tt = idx >> 4;                   // 0..135 triangular tile index
    int rb = 0;
    while ((rb + 1) * (rb + 2) / 2 <= tt) rb++;
    int cb = tt - rb * (rb + 1) / 2;     // 0..rb
    int t = threadIdx.x;
    int wave = t >> 6, l = t & 63;
    int wm = wave & 1, wn = wave >> 1;
    int quad = l >> 4, lr = l & 15;

    const u16* qbase = q16 + (size_t)(rb * 128 + wm * 64 + lr) * CDIM + h * HDIM + quad * 8;
    const u16* kbase = k16 + (size_t)(cb * 128 + wn * 64 + lr) * CDIM + h * HDIM + quad * 8;
    f16x8 qa[4][2], kf[4][2];
#pragma unroll
    for (int mi = 0; mi < 4; ++mi)
#pragma unroll
        for (int kb = 0; kb < 2; ++kb)
            qa[mi][kb] = *(const f16x8*)(qbase + (size_t)(mi * 16) * CDIM + kb * 32);
#pragma unroll
    for (int ni = 0; ni < 4; ++ni)
#pragma unroll
        for (int kb = 0; kb < 2; ++kb)
            kf[ni][kb] = *(const f16x8*)(kbase + (size_t)(ni * 16) * CDIM + kb * 32);

    f32x4 s[4][4];
#pragma unroll
    for (int mi = 0; mi < 4; ++mi)
#pragma unroll
        for (int ni = 0; ni < 4; ++ni) s[mi][ni] = (f32x4){0.f, 0.f, 0.f, 0.f};
#pragma unroll
    for (int kb = 0; kb < 2; ++kb)
#pragma unroll
        for (int mi = 0; mi < 4; ++mi)
#pragma unroll
            for (int ni = 0; ni < 4; ++ni)
                s[mi][ni] = __builtin_amdgcn_mfma_f32_16x16x32_f16(qa[mi][kb], kf[ni][kb], s[mi][ni], 0, 0, 0);

#pragma unroll
    for (int mi = 0; mi < 4; ++mi) {
        int row = wm * 64 + mi * 16 + quad * 4;
#pragma unroll
        for (int ni = 0; ni < 4; ++ni) {
            int col = wn * 64 + ni * 16 + lr;
#pragma unroll
            for (int rr = 0; rr < 4; ++rr) {
                bool valid = (cb < rb) | (col <= row + rr);   // same 128-block => local compare
                float p = valid ? __builtin_amdgcn_exp2f(s[mi][ni][rr] * EXP2C - 12.f) : 0.f;
                Pt[(row + rr) * 144 + col] = f2h(p);
            }
        }
    }
    __syncthreads();
    u16* Pg = P + (size_t)h * P_HSTR + (size_t)tt * P_TILE;
#pragma unroll
    for (int i = 0; i < 8; ++i) {
        int c = i * 256 + t;             // 2048 chunks of 8 elems
        int row = c >> 4, cw = c & 15;
        uint4 v = *(const uint4*)&Pt[row * 144 + cw * 8];
        *(uint4*)(Pg + row * 128 + cw * 8) = v;
    }
}

// ---- Kernel B: Z = P @ W, 8-wave paired-job blocks, T4 counted-vmcnt pipeline ----
// Rounds 7/8 were the m218 "drain0" null config: vmcnt(0) at EVERY phase end kills the
// prefetch (~300cy to land vs ~500-900cy L3 latency for P). Round-9 = real T4: depth-2
// prologue (stage 0 AND 1), steady-state waits are vmcnt(4) -- only the oldest stage
// must have landed; the newer one stays in flight across BOTH barriers and the whole
// compute phase (~one full step to land). vmcnt(0) only at the true tail. FIFO vmcnt
// semantics also order the inter-job Z-stores correctly (oldest complete first).
// Static buffer names (round 8) kept so LDS alias analysis can't force extra drains.
// Paired jobs kept (17 K-units/block, zero tail); 2 blocks/CU x 8 waves = 16 waves/CU.
// l = P.1 via ones-MFMA on nq==0, wc==0 waves; 1/l deferred to contract_y.
__global__ __launch_bounds__(512, 4) void pw_gemm(const u16* __restrict__ P,
                                                  const u16* __restrict__ W,
                                                  u16* __restrict__ Z,
                                                  float* __restrict__ lbuf) {
    __shared__ u16 A0s[8192], B0s[8192], A1s[8192], B1s[8192];
    int b = blockIdx.x;
    int jp = b >> 6;                     // 0..7 rb-pair index
    int i6 = b & 63;
    int h = ((i6 & 7) << 1) | ((i6 >> 3) & 1);
    int nq = i6 >> 4;
    const u16* Bt = W + (size_t)h * W_HSTR + (size_t)(nq * 128) * T_SEQ;
    u16* Zb = Z + (size_t)h * Z_HSTR;
    int t = threadIdx.x;
    int wave = t >> 6, l = t & 63;
    int wr = wave >> 1, wc = wave & 1;   // wave tile: rows wr*32, cols wc*64
    int quad = l >> 4, lr = l & 15;
    int acol = quad * 8;
    // per-wave staging slots d0,d1 (same fragment-major formulas as rounds 6-8)
    int d0 = wave * 2, d1 = wave * 2 + 1;
    int kq0 = d0 >> 3, sg0 = d0 & 7;
    int kq1 = d1 >> 3, sg1 = d1 & 7;
    size_t ro0 = (size_t)(sg0 * 16 + lr), ro1 = (size_t)(sg1 * 16 + lr);
    f16x8 ones;
#pragma unroll
    for (int j = 0; j < 8; ++j) ones[j] = (_Float16)1.0f;

    const u16* Ph;
    f32x4 acc[2][4];
    f32x4 accl[2];

    auto stage = [&](int k0, u16* Ad, u16* Bd) {
        const u16* At = Ph + (size_t)(k0 >> 7) * P_TILE + (k0 & 64);  // tile base + k-half
        gload16(At + ro0 * 128 + kq0 * 32 + acol, Ad + d0 * 512);
        gload16(Bt + ro0 * T_SEQ + k0 + kq0 * 32 + acol, Bd + d0 * 512);
        gload16(At + ro1 * 128 + kq1 * 32 + acol, Ad + d1 * 512);
        gload16(Bt + ro1 * T_SEQ + k0 + kq1 * 32 + acol, Bd + d1 * 512);
    };
    auto compute = [&](const u16* Asrc, const u16* Bsrc, bool dol) {
#pragma unroll
        for (int kb = 0; kb < 2; ++kb) {
            f16x8 af[2], bf[4];
#pragma unroll
            for (int mi = 0; mi < 2; ++mi) af[mi] = *(const f16x8*)&Asrc[(kb * 8 + wr * 2 + mi) * 512 + l * 8];
#pragma unroll
            for (int ni = 0; ni < 4; ++ni) bf[ni] = *(const f16x8*)&Bsrc[(kb * 8 + wc * 4 + ni) * 512 + l * 8];
#pragma unroll
            for (int mi = 0; mi < 2; ++mi) {
#pragma unroll
                for (int ni = 0; ni < 4; ++ni)
                    acc[mi][ni] = __builtin_amdgcn_mfma_f32_16x16x32_f16(af[mi], bf[ni], acc[mi][ni], 0, 0, 0);
                if (dol)
                    accl[mi] = __builtin_amdgcn_mfma_f32_16x16x32_f16(af[mi], ones, accl[mi], 0, 0, 0);
            }
        }
    };

#pragma unroll 1
    for (int jobi = 0; jobi < 2; ++jobi) {
        int rb = jobi ? jp : 15 - jp;    // heavy job first
        int nsteps = (rb + 1) * 2;       // K/64, always even, >= 2
        Ph = P + (size_t)h * P_HSTR + (size_t)(rb * (rb + 1) / 2) * P_TILE;
        bool dol = (nq == 0) && (wc == 0);
#pragma unroll
        for (int mi = 0; mi < 2; ++mi) {
            accl[mi] = (f32x4){0.f, 0.f, 0.f, 0.f};
#pragma unroll
            for (int ni = 0; ni < 4; ++ni) acc[mi][ni] = (f32x4){0.f, 0.f, 0.f, 0.f};
        }
        // depth-2 prologue: steps 0 and 1 both in flight (8 loads/wave)
        stage(0, A0s, B0s);
        stage(64, A1s, B1s);
#pragma unroll 1
        for (int s = 0; s < nsteps; s += 2) {
            // even phase: wait only for stage(s); stage(s+1) stays in flight
            asm volatile("s_waitcnt vmcnt(4)" ::: "memory");
            __builtin_amdgcn_s_barrier();
            compute(A0s, B0s, dol);
            __builtin_amdgcn_s_barrier();             // all waves done reading buf0
            if (s + 2 < nsteps) stage((s + 2) * 64, A0s, B0s);
            // odd phase
            if (s + 2 < nsteps) asm volatile("s_waitcnt vmcnt(4)" ::: "memory");
            else                asm volatile("s_waitcnt vmcnt(0)" ::: "memory");  // tail
            __builtin_amdgcn_s_barrier();
            compute(A1s, B1s, dol);
            __builtin_amdgcn_s_barrier();             // all waves done reading buf1
            if (s + 3 < nsteps) stage((s + 3) * 64, A1s, B1s);
        }
#pragma unroll
        for (int mi = 0; mi < 2; ++mi)
#pragma unroll
            for (int rr = 0; rr < 4; ++rr) {
                int row = rb * 128 + wr * 32 + mi * 16 + quad * 4 + rr;
#pragma unroll
                for (int ni = 0; ni < 4; ++ni) {
                    int col = nq * 128 + wc * 64 + ni * 16 + lr;
                    Zb[(size_t)row * 512 + col] = f2h(acc[mi][ni][rr]);
                }
            }
        if (dol && lr == 0) {
#pragma unroll
            for (int mi = 0; mi < 2; ++mi) {
                int row = rb * 128 + wr * 32 + mi * 16 + quad * 4;
                *(f32x4*)(lbuf + h * T_SEQ + row) = accl[mi];
            }
        }
    }
}

// fp32 -> fp16 conversions: z=0 x(2M), z=1..4 Wq/Wk/Wv/Wo (1M each) into w16
__global__ __launch_bounds__(256) void cvt5(const float* __restrict__ x, const float* __restrict__ wq,
                                            const float* __restrict__ wk, const float* __restrict__ wv,
                                            const float* __restrict__ wo,
                                            u16* __restrict__ x16, u16* __restrict__ w16) {
    int z = blockIdx.y;
    size_t base = ((size_t)blockIdx.x * 256 + threadIdx.x) * 8;
    const float* src;
    u16* dst;
    size_t cnt;
    if (z == 0) { src = x; dst = x16; cnt = 2097152; }
    else if (z == 1) { src = wq; dst = w16; cnt = 1048576; }
    else if (z == 2) { src = wk; dst = w16 + 1048576; cnt = 1048576; }
    else if (z == 3) { src = wv; dst = w16 + 2097152; cnt = 1048576; }
    else { src = wo; dst = w16 + 3145728; cnt = 1048576; }
    if (base >= cnt) return;
    float4 f0 = *(const float4*)(src + base);
    float4 f1 = *(const float4*)(src + base + 4);
    uint4 o;
    o.x = pk(f0.x, f0.y); o.y = pk(f0.z, f0.w); o.z = pk(f1.x, f1.y); o.w = pk(f1.z, f1.w);
    *(uint4*)(dst + base) = o;
}

// One wave per (t,h): rotary+RMS from fp16 qkv (ld 3072); writes q16,k16 (fp16), kc (fp32).
__global__ __launch_bounds__(256) void prep_rope(const u16* __restrict__ qkv,
                                                 u16* __restrict__ q16, u16* __restrict__ k16,
                                                 float* __restrict__ kc,
                                                 const float* __restrict__ cosb, const float* __restrict__ sinb) {
    int wave = threadIdx.x >> 6, lane = threadIdx.x & 63;
    int idx = blockIdx.x * 4 + wave;
    int t = idx >> 4, h = idx & 15;
    int d = lane & 31;
    float cs = cosb[t * 32 + d];
    float sn = sinb[t * 32 + d];
    size_t b3 = (size_t)t * 3072 + h * HDIM;
    size_t b1 = (size_t)t * CDIM + h * HDIM;

    float xq = h2f(qkv[b3 + lane]);
    float oq = __shfl(xq, lane ^ 32);
    float rq = (lane < 32) ? fmaf(xq, cs, oq * sn) : fmaf(xq, cs, -oq * sn);
    float ssq = rq * rq;
#pragma unroll
    for (int m = 1; m < 64; m <<= 1) ssq += __shfl_xor(ssq, m);
    rq *= rsqrtf(ssq * (1.f / 64.f) + 1e-6f);
    q16[b1 + lane] = f2h(rq);

    float xk = h2f(qkv[b3 + 1024 + lane]);
    float ok = __shfl(xk, lane ^ 32);
    float rk = (lane < 32) ? fmaf(xk, cs, ok * sn) : fmaf(xk, cs, -ok * sn);
    float ssk = rk * rk;
#pragma unroll
    for (int m = 1; m < 64; m <<= 1) ssk += __shfl_xor(ssk, m);
    rk *= rsqrtf(ssk * (1.f / 64.f) + 1e-6f);
    k16[b1 + lane] = f2h(rk);

    float s8 = rk * rk;
    s8 += __shfl_xor(s8, 1); s8 += __shfl_xor(s8, 2); s8 += __shfl_xor(s8, 4);
    float sc2 = 1.f / fmaxf(sqrtf(s8), 1e-12f);
    float kcv = rk * sc2;
    if (lane & 7) kcv = -kcv;  // octonion conjugate
    kc[b1 + lane] = kcv;
}

// W[h][n=(m*64+a*8+e)][j] from kc (fp32, ld 1024) and v inside fp16 qkv (ld 3072, +2048)
__global__ __launch_bounds__(256) void w_pre(const float* __restrict__ kc, const u16* __restrict__ qkv,
                                             u16* __restrict__ W) {
    __shared__ float kcs[64][65];
    __shared__ float vs[64][65];
    int h = blockIdx.y;
    int j0 = blockIdx.x * 64;
    int t = threadIdx.x;
    int r = t >> 2, cq = (t & 3) * 16;
    const float* kp = kc + (size_t)(j0 + r) * CDIM + h * HDIM + cq;
    const u16* vp = qkv + (size_t)(j0 + r) * 3072 + 2048 + h * HDIM + cq;
#pragma unroll
    for (int u4 = 0; u4 < 4; ++u4) {
        float4 a = *(const float4*)(kp + u4 * 4);
        ushort4 b = *(const ushort4*)(vp + u4 * 4);
        kcs[r][cq + u4 * 4 + 0] = a.x; kcs[r][cq + u4 * 4 + 1] = a.y;
        kcs[r][cq + u4 * 4 + 2] = a.z; kcs[r][cq + u4 * 4 + 3] = a.w;
        vs[r][cq + u4 * 4 + 0] = h2f(b.x); vs[r][cq + u4 * 4 + 1] = h2f(b.y);
        vs[r][cq + u4 * 4 + 2] = h2f(b.z); vs[r][cq + u4 * 4 + 3] = h2f(b.w);
    }
    __syncthreads();
    int j = t & 63, g = t >> 6;
    u16* Wp = W + (size_t)h * W_HSTR + j0 + j;
    for (int ae = g * 16; ae < g * 16 + 16; ++ae) {
        int a = ae >> 3, e = ae & 7;
        u32 mask = 0;
#pragma unroll
        for (int qq = 0; qq < 8; ++qq) {
            int p = a ^ e ^ qq;
            u32 bit = (u32)(((SGBITS >> (a * 8 + p)) ^ (SGBITS >> ((e ^ qq) * 8 + qq))) & 1ULL);
            mask |= bit << qq;
        }
#pragma unroll
        for (int m = 0; m < 8; ++m) {
            float w = 0.f;
#pragma unroll
            for (int qq = 0; qq < 8; ++qq) {
                float t1 = kcs[j][m * 8 + (a ^ e ^ qq)] * vs[j][m * 8 + qq];
                w = ((mask >> qq) & 1) ? (w - t1) : (w + t1);
            }
            Wp[(size_t)(m * 64 + ae) * T_SEQ] = f2h(w);
        }
    }
}

// y16[i, h*64+m*8+e] = (sum_a q16[..m*8+a] * Z'[h][i][m*64+a*8+e]) / l[h][i]
__global__ __launch_bounds__(256) void contract_y(const u16* __restrict__ q16, const u16* __restrict__ Z,
                                                  const float* __restrict__ lbuf, u16* __restrict__ y16) {
    __shared__ u16 zb[4][512];
    int wave = threadIdx.x >> 6, lane = threadIdx.x & 63;
    int idx = blockIdx.x * 4 + wave;
    int i = idx >> 4, h = idx & 15;
    uint4 zv = *(const uint4*)(Z + (size_t)h * Z_HSTR + (size_t)i * 512 + lane * 8);
    *(uint4*)&zb[wave][lane * 8] = zv;
    int m = lane >> 3, e = lane & 7;
    const u16* qp = q16 + (size_t)i * CDIM + h * HDIM + m * 8;
    uint4 qb = *(const uint4*)qp;
    float qv[8];
    qv[0] = h2f(qb.x & 0xffff); qv[1] = h2f(qb.x >> 16);
    qv[2] = h2f(qb.y & 0xffff); qv[3] = h2f(qb.y >> 16);
    qv[4] = h2f(qb.z & 0xffff); qv[5] = h2f(qb.z >> 16);
    qv[6] = h2f(qb.w & 0xffff); qv[7] = h2f(qb.w >> 16);
    float linv = 1.f / lbuf[h * T_SEQ + i];
    __syncthreads();
    float acc = 0.f;
#pragma unroll
    for (int a = 0; a < 8; ++a) acc = fmaf(qv[a], h2f(zb[wave][m * 64 + a * 8 + e]), acc);
    y16[(size_t)i * CDIM + h * HDIM + lane] = f2h(acc * linv);
}

extern "C" void kernel_launch(void* const* d_in, const int* in_sizes, int n_in,
                              void* d_out, int out_size, void* d_ws, size_t ws_size,
                              hipStream_t stream) {
    const float* x = (const float*)d_in[0];
    const float* cosb = (const float*)d_in[1];
    const float* sinb = (const float*)d_in[2];
    const float* Wq = (const float*)d_in[3];
    const float* Wk = (const float*)d_in[4];
    const float* Wv = (const float*)d_in[5];
    const float* Wo = (const float*)d_in[6];
    float* out = (float*)d_out;
    char* base = (char*)d_ws;
    // workspace layout (~185 MB total; ws >= 243 MB proven)
    u16* qkv16 = (u16*)base;                      // 2048x3072 fp16   12,582,912 B
    float* kc = (float*)(base + 12582912);        // 2048x1024 fp32    8,388,608
    u16* x16 = (u16*)(base + 20971520);           //                   4,194,304
    u16* w16 = (u16*)(base + 25165824);           // 4x 1024x1024 fp16 8,388,608
    u16* q16 = (u16*)(base + 33554432);           //                   4,194,304
    u16* k16 = (u16*)(base + 37748736);           //                   4,194,304
    u16* y16 = (u16*)(base + 41943040);           //                   4,194,304
    u16* W = (u16*)(base + 46137344);             //                  33,554,432
    u16* Z = (u16*)(base + 79691776);             //                  33,554,432
    float* lbuf = (float*)(base + 113246208);     // 16x2048 fp32        131,072
    u16* Pbuf = (u16*)(base + 113377280);         // 16x136 tiles fp16 71,303,168 -> end 184,680,448

    cvt5<<<dim3(1024, 5), 256, 0, stream>>>(x, Wq, Wk, Wv, Wo, x16, w16);
    hgemm_f16<<<dim3(24, 16), 256, 0, stream>>>(x16, CDIM, w16, CDIM, qkv16, 3072, CDIM);
    prep_rope<<<T_SEQ * NHEAD / 4, 256, 0, stream>>>(qkv16, q16, k16, kc, cosb, sinb);
    qk_exp_p<<<16 * 136, 256, 0, stream>>>(q16, k16, Pbuf);
    w_pre<<<dim3(32, 16), 256, 0, stream>>>(kc, qkv16, W);
    pw_gemm<<<512, 512, 0, stream>>>(Pbuf, W, Z, lbuf);
    contract_y<<<NHEAD * T_SEQ / 4, 256, 0, stream>>>(q16, Z, lbuf, y16);
    hgemm_f32<<<dim3(8, 16), 256, 0, stream>>>(y16, CDIM, w16 + 3145728, CDIM, out, CDIM, CDIM);
}

// Round 10
// 279.694 us; speedup vs baseline: 1.0187x; 1.0157x over previous
//
#include <hip/hip_runtime.h>

typedef unsigned short u16;
typedef unsigned int u32;

#define T_SEQ 2048
#define NHEAD 16
#define HDIM 64
#define CDIM 1024
#define W_HSTR (512*2048)
#define Z_HSTR (2048*512)
// P: per head 136 causal tiles of 128x128 fp16, row-major tiles
#define P_HSTR 2228224   // 136*16384 elems
#define P_TILE 16384

// Octonion sign table: SG[a][n] = sign of component (a^n) of e_a * e_n.
// Byte a holds row a; bit n set => negative. (Validated end-to-end rounds 3-8.)
#define SGBITS 0xB2D8741EACC66A00ULL

// exp(s*0.125) = exp2(s*0.125/ln2); extra 2^-12 scale keeps unnormalized Z in fp16 range.
#define EXP2C 0.18033688011112042f

typedef _Float16 f16x8 __attribute__((ext_vector_type(8)));
typedef float f32x4 __attribute__((ext_vector_type(4)));

__device__ __forceinline__ float h2f(u16 u) { _Float16 h; __builtin_memcpy(&h, &u, 2); return (float)h; }
__device__ __forceinline__ u16 f2h(float f) { _Float16 h = (_Float16)f; u16 u; __builtin_memcpy(&u, &h, 2); return u; }
__device__ __forceinline__ u32 pk(float a, float b) { return (u32)f2h(a) | ((u32)f2h(b) << 16); }

// async 16B/lane global->LDS DMA; lds dest wave-uniform (HW adds lane*16)
__device__ __forceinline__ void gload16(const u16* g, u16* l) {
    __builtin_amdgcn_global_load_lds((const __attribute__((address_space(1))) u32*)g,
                                     (__attribute__((address_space(3))) u32*)l, 16, 0, 0);
}

// ---- 64x128-tile MFMA core (round-10: grid utilization for skinny GEMMs) ----
// Same fragment-major LDS scheme as the proven 128x128 core, A halved (seg 0..3).
// 256 threads = 4 waves as 2 wr x 2 wc; wave tile 32x64, acc[2][4].
// LDS 24KB -> many blocks/CU; hgemm_f16 768 blocks (3/CU), hgemm_f32 256 (1/CU, all CUs).
template<bool F16OUT>
__device__ __forceinline__ void hgemm64_tile(const u16* __restrict__ At, int lda,
                                             const u16* __restrict__ Bt, int ldb, int K,
                                             float* __restrict__ Cf, u16* __restrict__ Ch,
                                             int ldc, u16* As, u16* Bs) {
    int t = threadIdx.x;
    int wave = t >> 6, l = t & 63;
    int wr = wave & 1, wc = wave >> 1;
    int quad = l >> 4, lr = l & 15;
    int acol = quad * 8;
    f32x4 acc[2][4];
#pragma unroll
    for (int i = 0; i < 2; ++i)
#pragma unroll
        for (int j = 0; j < 4; ++j) acc[i][j] = (f32x4){0.f, 0.f, 0.f, 0.f};
    for (int k0 = 0; k0 < K; k0 += 64) {
#pragma unroll
        for (int j = 0; j < 2; ++j) {           // A slots: 8 total (kb 0..1 x seg 0..3)
            int dA = wave * 2 + j;
            int kb = dA >> 2, seg = dA & 3;
            gload16(At + (size_t)(seg * 16 + lr) * lda + k0 + kb * 32 + acol, As + dA * 512);
        }
#pragma unroll
        for (int j = 0; j < 4; ++j) {           // B slots: 16 total (kb 0..1 x seg 0..7)
            int dB = wave * 4 + j;
            int kb = dB >> 3, seg = dB & 7;
            gload16(Bt + (size_t)(seg * 16 + lr) * ldb + k0 + kb * 32 + acol, Bs + dB * 512);
        }
        __syncthreads();
#pragma unroll
        for (int kb = 0; kb < 2; ++kb) {
            f16x8 af[2], bf[4];
#pragma unroll
            for (int mi = 0; mi < 2; ++mi) af[mi] = *(const f16x8*)&As[(kb * 4 + wr * 2 + mi) * 512 + l * 8];
#pragma unroll
            for (int ni = 0; ni < 4; ++ni) bf[ni] = *(const f16x8*)&Bs[(kb * 8 + wc * 4 + ni) * 512 + l * 8];
#pragma unroll
            for (int mi = 0; mi < 2; ++mi)
#pragma unroll
                for (int ni = 0; ni < 4; ++ni)
                    acc[mi][ni] = __builtin_amdgcn_mfma_f32_16x16x32_f16(af[mi], bf[ni], acc[mi][ni], 0, 0, 0);
        }
        __syncthreads();
    }
#pragma unroll
    for (int mi = 0; mi < 2; ++mi)
#pragma unroll
        for (int ni = 0; ni < 4; ++ni)
#pragma unroll
            for (int rr = 0; rr < 4; ++rr) {
                int gr = wr * 32 + mi * 16 + quad * 4 + rr;
                int gc = wc * 64 + ni * 16 + lr;
                float v = acc[mi][ni][rr];
                if (F16OUT) Ch[(size_t)gr * ldc + gc] = f2h(v);
                else Cf[(size_t)gr * ldc + gc] = v;
            }
}

__global__ __launch_bounds__(256) void hgemm_f32(const u16* __restrict__ A, int lda,
                                                 const u16* __restrict__ B, int ldb,
                                                 float* __restrict__ C, int ldc, int K) {
    __shared__ u16 As[4096], Bs[8192];
    int bm = blockIdx.y * 64, bn = blockIdx.x * 128;
    hgemm64_tile<false>(A + (size_t)bm * lda, lda, B + (size_t)bn * ldb, ldb, K,
                        C + (size_t)bm * ldc + bn, nullptr, ldc, As, Bs);
}

__global__ __launch_bounds__(256) void hgemm_f16(const u16* __restrict__ A, int lda,
                                                 const u16* __restrict__ B, int ldb,
                                                 u16* __restrict__ C, int ldc, int K) {
    __shared__ u16 As[4096], Bs[8192];
    int bm = blockIdx.y * 64, bn = blockIdx.x * 128;
    hgemm64_tile<true>(A + (size_t)bm * lda, lda, B + (size_t)bn * ldb, ldb, K,
                       nullptr, C + (size_t)bm * ldc + bn, ldc, As, Bs);
}

// ---- Kernel A: one-shot P = exp(QK^T) per 128x128 causal tile ----
// 2176 blocks = 16 heads x 136 tiles (rb>=cb). QK direct from global (L2-resident),
// exp -> LDS (round-0 expst pattern), then coalesced row-major uint4 tile store.
// LDS pad 144 keeps 16B alignment for the uint4 re-read (144*2 = 288 = 18*16).
__global__ __launch_bounds__(256) void qk_exp_p(const u16* __restrict__ q16,
                                                const u16* __restrict__ k16,
                                                u16* __restrict__ P) {
    __shared__ u16 Pt[128 * 144];
    int idx = blockIdx.x;
    int h = idx & 15;
    int tt = idx >> 4;                   // 0..135 triangular tile index
    int rb = 0;
    while ((rb + 1) * (rb + 2) / 2 <= tt) rb++;
    int cb = tt - rb * (rb + 1) / 2;     // 0..rb
    int t = threadIdx.x;
    int wave = t >> 6, l = t & 63;
    int wm = wave & 1, wn = wave >> 1;
    int quad = l >> 4, lr = l & 15;

    const u16* qbase = q16 + (size_t)(rb * 128 + wm * 64 + lr) * CDIM + h * HDIM + quad * 8;
    const u16* kbase = k16 + (size_t)(cb * 128 + wn * 64 + lr) * CDIM + h * HDIM + quad * 8;
    f16x8 qa[4][2], kf[4][2];
#pragma unroll
    for (int mi = 0; mi < 4; ++mi)
#pragma unroll
        for (int kb = 0; kb < 2; ++kb)
            qa[mi][kb] = *(const f16x8*)(qbase + (size_t)(mi * 16) * CDIM + kb * 32);
#pragma unroll
    for (int ni = 0; ni < 4; ++ni)
#pragma unroll
        for (int kb = 0; kb < 2; ++kb)
            kf[ni][kb] = *(const f16x8*)(kbase + (size_t)(ni * 16) * CDIM + kb * 32);

    f32x4 s[4][4];
#pragma unroll
    for (int mi = 0; mi < 4; ++mi)
#pragma unroll
        for (int ni = 0; ni < 4; ++ni) s[mi][ni] = (f32x4){0.f, 0.f, 0.f, 0.f};
#pragma unroll
    for (int kb = 0; kb < 2; ++kb)
#pragma unroll
        for (int mi = 0; mi < 4; ++mi)
#pragma unroll
            for (int ni = 0; ni < 4; ++ni)
                s[mi][ni] = __builtin_amdgcn_mfma_f32_16x16x32_f16(qa[mi][kb], kf[ni][kb], s[mi][ni], 0, 0, 0);

#pragma unroll
    for (int mi = 0; mi < 4; ++mi) {
        int row = wm * 64 + mi * 16 + quad * 4;
#pragma unroll
        for (int ni = 0; ni < 4; ++ni) {
            int col = wn * 64 + ni * 16 + lr;
#pragma unroll
            for (int rr = 0; rr < 4; ++rr) {
                bool valid = (cb < rb) | (col <= row + rr);   // same 128-block => local compare
                float p = valid ? __builtin_amdgcn_exp2f(s[mi][ni][rr] * EXP2C - 12.f) : 0.f;
                Pt[(row + rr) * 144 + col] = f2h(p);
            }
        }
    }
    __syncthreads();
    u16* Pg = P + (size_t)h * P_HSTR + (size_t)tt * P_TILE;
#pragma unroll
    for (int i = 0; i < 8; ++i) {
        int c = i * 256 + t;             // 2048 chunks of 8 elems
        int row = c >> 4, cw = c & 15;
        uint4 v = *(const uint4*)&Pt[row * 144 + cw * 8];
        *(uint4*)(Pg + row * 128 + cw * 8) = v;
    }
}

// ---- Kernel B: Z = P @ W, 8-wave blocks, paired jobs (round-6 proven version) ----
// Grid 512, 512 threads. Block b: jp = b>>6; runs rb = 15-jp then rb = jp ->
// exactly 17 K-units per block, all blocks identical duration. 2 blocks/CU x 8 waves
// = 16 waves/CU flat. Per wave: 32x64 output (acc[2][4]; VGPR 48, no spill).
// Rounds 7-9 established this structure's ~77us floor is NOT load-latency (three
// pipeline schedules all null); keep the simplest single-buffer form.
// l = P.1 via ones-MFMA on nq==0, wc==0 waves; 1/l deferred to contract_y.
__global__ __launch_bounds__(512, 4) void pw_gemm(const u16* __restrict__ P,
                                                  const u16* __restrict__ W,
                                                  u16* __restrict__ Z,
                                                  float* __restrict__ lbuf) {
    __shared__ u16 As[8192], Bs[8192];
    int b = blockIdx.x;
    int jp = b >> 6;                     // 0..7 rb-pair index
    int i6 = b & 63;
    int h = ((i6 & 7) << 1) | ((i6 >> 3) & 1);
    int nq = i6 >> 4;
    const u16* Bt = W + (size_t)h * W_HSTR + (size_t)(nq * 128) * T_SEQ;
    u16* Zb = Z + (size_t)h * Z_HSTR;
    int t = threadIdx.x;
    int wave = t >> 6, l = t & 63;
    int wr = wave >> 1, wc = wave & 1;   // wave tile: rows wr*32, cols wc*64
    int quad = l >> 4, lr = l & 15;
    int acol = quad * 8;
    f16x8 ones;
#pragma unroll
    for (int j = 0; j < 8; ++j) ones[j] = (_Float16)1.0f;

#pragma unroll 1
    for (int jobi = 0; jobi < 2; ++jobi) {
        int rb = jobi ? jp : 15 - jp;    // heavy job first
        int K = (rb + 1) * 128;
        const u16* Ph = P + (size_t)h * P_HSTR + (size_t)(rb * (rb + 1) / 2) * P_TILE;
        f32x4 acc[2][4];
        f32x4 accl[2];
#pragma unroll
        for (int mi = 0; mi < 2; ++mi) {
            accl[mi] = (f32x4){0.f, 0.f, 0.f, 0.f};
#pragma unroll
            for (int ni = 0; ni < 4; ++ni) acc[mi][ni] = (f32x4){0.f, 0.f, 0.f, 0.f};
        }
        for (int k0 = 0; k0 < K; k0 += 64) {
            const u16* At = Ph + (size_t)(k0 >> 7) * P_TILE + (k0 & 64);  // tile base + k-half
#pragma unroll
            for (int j = 0; j < 2; ++j) {
                int d = wave * 2 + j;
                int kb = d >> 3, seg = d & 7;
                size_t roff = (size_t)(seg * 16 + lr);
                gload16(At + roff * 128 + kb * 32 + acol, As + d * 512);
                gload16(Bt + roff * T_SEQ + k0 + kb * 32 + acol, Bs + d * 512);
            }
            __syncthreads();
#pragma unroll
            for (int kb = 0; kb < 2; ++kb) {
                f16x8 af[2], bf[4];
#pragma unroll
                for (int mi = 0; mi < 2; ++mi) af[mi] = *(const f16x8*)&As[(kb * 8 + wr * 2 + mi) * 512 + l * 8];
#pragma unroll
                for (int ni = 0; ni < 4; ++ni) bf[ni] = *(const f16x8*)&Bs[(kb * 8 + wc * 4 + ni) * 512 + l * 8];
#pragma unroll
                for (int mi = 0; mi < 2; ++mi) {
#pragma unroll
                    for (int ni = 0; ni < 4; ++ni)
                        acc[mi][ni] = __builtin_amdgcn_mfma_f32_16x16x32_f16(af[mi], bf[ni], acc[mi][ni], 0, 0, 0);
                    if (nq == 0 && wc == 0)
                        accl[mi] = __builtin_amdgcn_mfma_f32_16x16x32_f16(af[mi], ones, accl[mi], 0, 0, 0);
                }
            }
            __syncthreads();
        }
#pragma unroll
        for (int mi = 0; mi < 2; ++mi)
#pragma unroll
            for (int rr = 0; rr < 4; ++rr) {
                int row = rb * 128 + wr * 32 + mi * 16 + quad * 4 + rr;
#pragma unroll
                for (int ni = 0; ni < 4; ++ni) {
                    int col = nq * 128 + wc * 64 + ni * 16 + lr;
                    Zb[(size_t)row * 512 + col] = f2h(acc[mi][ni][rr]);
                }
            }
        if (nq == 0 && wc == 0 && lr == 0) {
#pragma unroll
            for (int mi = 0; mi < 2; ++mi) {
                int row = rb * 128 + wr * 32 + mi * 16 + quad * 4;
                *(f32x4*)(lbuf + h * T_SEQ + row) = accl[mi];
            }
        }
    }
}

// fp32 -> fp16 conversions: z=0 x(2M), z=1..4 Wq/Wk/Wv/Wo (1M each) into w16
__global__ __launch_bounds__(256) void cvt5(const float* __restrict__ x, const float* __restrict__ wq,
                                            const float* __restrict__ wk, const float* __restrict__ wv,
                                            const float* __restrict__ wo,
                                            u16* __restrict__ x16, u16* __restrict__ w16) {
    int z = blockIdx.y;
    size_t base = ((size_t)blockIdx.x * 256 + threadIdx.x) * 8;
    const float* src;
    u16* dst;
    size_t cnt;
    if (z == 0) { src = x; dst = x16; cnt = 2097152; }
    else if (z == 1) { src = wq; dst = w16; cnt = 1048576; }
    else if (z == 2) { src = wk; dst = w16 + 1048576; cnt = 1048576; }
    else if (z == 3) { src = wv; dst = w16 + 2097152; cnt = 1048576; }
    else { src = wo; dst = w16 + 3145728; cnt = 1048576; }
    if (base >= cnt) return;
    float4 f0 = *(const float4*)(src + base);
    float4 f1 = *(const float4*)(src + base + 4);
    uint4 o;
    o.x = pk(f0.x, f0.y); o.y = pk(f0.z, f0.w); o.z = pk(f1.x, f1.y); o.w = pk(f1.z, f1.w);
    *(uint4*)(dst + base) = o;
}

// One wave per (t,h): rotary+RMS from fp16 qkv (ld 3072); writes q16,k16 (fp16), kc (fp32).
__global__ __launch_bounds__(256) void prep_rope(const u16* __restrict__ qkv,
                                                 u16* __restrict__ q16, u16* __restrict__ k16,
                                                 float* __restrict__ kc,
                                                 const float* __restrict__ cosb, const float* __restrict__ sinb) {
    int wave = threadIdx.x >> 6, lane = threadIdx.x & 63;
    int idx = blockIdx.x * 4 + wave;
    int t = idx >> 4, h = idx & 15;
    int d = lane & 31;
    float cs = cosb[t * 32 + d];
    float sn = sinb[t * 32 + d];
    size_t b3 = (size_t)t * 3072 + h * HDIM;
    size_t b1 = (size_t)t * CDIM + h * HDIM;

    float xq = h2f(qkv[b3 + lane]);
    float oq = __shfl(xq, lane ^ 32);
    float rq = (lane < 32) ? fmaf(xq, cs, oq * sn) : fmaf(xq, cs, -oq * sn);
    float ssq = rq * rq;
#pragma unroll
    for (int m = 1; m < 64; m <<= 1) ssq += __shfl_xor(ssq, m);
    rq *= rsqrtf(ssq * (1.f / 64.f) + 1e-6f);
    q16[b1 + lane] = f2h(rq);

    float xk = h2f(qkv[b3 + 1024 + lane]);
    float ok = __shfl(xk, lane ^ 32);
    float rk = (lane < 32) ? fmaf(xk, cs, ok * sn) : fmaf(xk, cs, -ok * sn);
    float ssk = rk * rk;
#pragma unroll
    for (int m = 1; m < 64; m <<= 1) ssk += __shfl_xor(ssk, m);
    rk *= rsqrtf(ssk * (1.f / 64.f) + 1e-6f);
    k16[b1 + lane] = f2h(rk);

    float s8 = rk * rk;
    s8 += __shfl_xor(s8, 1); s8 += __shfl_xor(s8, 2); s8 += __shfl_xor(s8, 4);
    float sc2 = 1.f / fmaxf(sqrtf(s8), 1e-12f);
    float kcv = rk * sc2;
    if (lane & 7) kcv = -kcv;  // octonion conjugate
    kc[b1 + lane] = kcv;
}

// W[h][n=(m*64+a*8+e)][j] from kc (fp32, ld 1024) and v inside fp16 qkv (ld 3072, +2048)
__global__ __launch_bounds__(256) void w_pre(const float* __restrict__ kc, const u16* __restrict__ qkv,
                                             u16* __restrict__ W) {
    __shared__ float kcs[64][65];
    __shared__ float vs[64][65];
    int h = blockIdx.y;
    int j0 = blockIdx.x * 64;
    int t = threadIdx.x;
    int r = t >> 2, cq = (t & 3) * 16;
    const float* kp = kc + (size_t)(j0 + r) * CDIM + h * HDIM + cq;
    const u16* vp = qkv + (size_t)(j0 + r) * 3072 + 2048 + h * HDIM + cq;
#pragma unroll
    for (int u4 = 0; u4 < 4; ++u4) {
        float4 a = *(const float4*)(kp + u4 * 4);
        ushort4 b = *(const ushort4*)(vp + u4 * 4);
        kcs[r][cq + u4 * 4 + 0] = a.x; kcs[r][cq + u4 * 4 + 1] = a.y;
        kcs[r][cq + u4 * 4 + 2] = a.z; kcs[r][cq + u4 * 4 + 3] = a.w;
        vs[r][cq + u4 * 4 + 0] = h2f(b.x); vs[r][cq + u4 * 4 + 1] = h2f(b.y);
        vs[r][cq + u4 * 4 + 2] = h2f(b.z); vs[r][cq + u4 * 4 + 3] = h2f(b.w);
    }
    __syncthreads();
    int j = t & 63, g = t >> 6;
    u16* Wp = W + (size_t)h * W_HSTR + j0 + j;
    for (int ae = g * 16; ae < g * 16 + 16; ++ae) {
        int a = ae >> 3, e = ae & 7;
        u32 mask = 0;
#pragma unroll
        for (int qq = 0; qq < 8; ++qq) {
            int p = a ^ e ^ qq;
            u32 bit = (u32)(((SGBITS >> (a * 8 + p)) ^ (SGBITS >> ((e ^ qq) * 8 + qq))) & 1ULL);
            mask |= bit << qq;
        }
#pragma unroll
        for (int m = 0; m < 8; ++m) {
            float w = 0.f;
#pragma unroll
            for (int qq = 0; qq < 8; ++qq) {
                float t1 = kcs[j][m * 8 + (a ^ e ^ qq)] * vs[j][m * 8 + qq];
                w = ((mask >> qq) & 1) ? (w - t1) : (w + t1);
            }
            Wp[(size_t)(m * 64 + ae) * T_SEQ] = f2h(w);
        }
    }
}

// y16[i, h*64+m*8+e] = (sum_a q16[..m*8+a] * Z'[h][i][m*64+a*8+e]) / l[h][i]
__global__ __launch_bounds__(256) void contract_y(const u16* __restrict__ q16, const u16* __restrict__ Z,
                                                  const float* __restrict__ lbuf, u16* __restrict__ y16) {
    __shared__ u16 zb[4][512];
    int wave = threadIdx.x >> 6, lane = threadIdx.x & 63;
    int idx = blockIdx.x * 4 + wave;
    int i = idx >> 4, h = idx & 15;
    uint4 zv = *(const uint4*)(Z + (size_t)h * Z_HSTR + (size_t)i * 512 + lane * 8);
    *(uint4*)&zb[wave][lane * 8] = zv;
    int m = lane >> 3, e = lane & 7;
    const u16* qp = q16 + (size_t)i * CDIM + h * HDIM + m * 8;
    uint4 qb = *(const uint4*)qp;
    float qv[8];
    qv[0] = h2f(qb.x & 0xffff); qv[1] = h2f(qb.x >> 16);
    qv[2] = h2f(qb.y & 0xffff); qv[3] = h2f(qb.y >> 16);
    qv[4] = h2f(qb.z & 0xffff); qv[5] = h2f(qb.z >> 16);
    qv[6] = h2f(qb.w & 0xffff); qv[7] = h2f(qb.w >> 16);
    float linv = 1.f / lbuf[h * T_SEQ + i];
    __syncthreads();
    float acc = 0.f;
#pragma unroll
    for (int a = 0; a < 8; ++a) acc = fmaf(qv[a], h2f(zb[wave][m * 64 + a * 8 + e]), acc);
    y16[(size_t)i * CDIM + h * HDIM + lane] = f2h(acc * linv);
}

extern "C" void kernel_launch(void* const* d_in, const int* in_sizes, int n_in,
                              void* d_out, int out_size, void* d_ws, size_t ws_size,
                              hipStream_t stream) {
    const float* x = (const float*)d_in[0];
    const float* cosb = (const float*)d_in[1];
    const float* sinb = (const float*)d_in[2];
    const float* Wq = (const float*)d_in[3];
    const float* Wk = (const float*)d_in[4];
    const float* Wv = (const float*)d_in[5];
    const float* Wo = (const float*)d_in[6];
    float* out = (float*)d_out;
    char* base = (char*)d_ws;
    // workspace layout (~185 MB total; ws >= 243 MB proven)
    u16* qkv16 = (u16*)base;                      // 2048x3072 fp16   12,582,912 B
    float* kc = (float*)(base + 12582912);        // 2048x1024 fp32    8,388,608
    u16* x16 = (u16*)(base + 20971520);           //                   4,194,304
    u16* w16 = (u16*)(base + 25165824);           // 4x 1024x1024 fp16 8,388,608
    u16* q16 = (u16*)(base + 33554432);           //                   4,194,304
    u16* k16 = (u16*)(base + 37748736);           //                   4,194,304
    u16* y16 = (u16*)(base + 41943040);           //                   4,194,304
    u16* W = (u16*)(base + 46137344);             //                  33,554,432
    u16* Z = (u16*)(base + 79691776);             //                  33,554,432
    float* lbuf = (float*)(base + 113246208);     // 16x2048 fp32        131,072
    u16* Pbuf = (u16*)(base + 113377280);         // 16x136 tiles fp16 71,303,168 -> end 184,680,448

    cvt5<<<dim3(1024, 5), 256, 0, stream>>>(x, Wq, Wk, Wv, Wo, x16, w16);
    hgemm_f16<<<dim3(24, 32), 256, 0, stream>>>(x16, CDIM, w16, CDIM, qkv16, 3072, CDIM);
    prep_rope<<<T_SEQ * NHEAD / 4, 256, 0, stream>>>(qkv16, q16, k16, kc, cosb, sinb);
    qk_exp_p<<<16 * 136, 256, 0, stream>>>(q16, k16, Pbuf);
    w_pre<<<dim3(32, 16), 256, 0, stream>>>(kc, qkv16, W);
    pw_gemm<<<512, 512, 0, stream>>>(Pbuf, W, Z, lbuf);
    contract_y<<<NHEAD * T_SEQ / 4, 256, 0, stream>>>(q16, Z, lbuf, y16);
    hgemm_f32<<<dim3(8, 32), 256, 0, stream>>>(y16, CDIM, w16 + 3145728, CDIM, out, CDIM, CDIM);
}